// Round 1
// baseline (62.921 us; speedup 1.0000x reference)
//
#include <hip/hip_runtime.h>

// Problem constants (B,S,D,R) = (4,1024,1024,64)
#define SS 1024
#define DD 1024
#define RR 64
#define NB 4
#define NROWS (NB * SS)   // 4096

#define KSPLIT 8
#define KSLICE (DD / KSPLIT)  // 128

// ---------------------------------------------------------------------------
// Kernel A: t[row][r] = sum_k batch[row][k] * proj[k][r]
// grid (NROWS/64, KSPLIT), block 256 (4 waves). Each wave: 16 rows, lane = r.
// K split across blockIdx.y; partials combined via fp32 atomicAdd into a
// zeroed workspace. Row addresses are wave-uniform -> scalar loads.
// ---------------------------------------------------------------------------
__global__ __launch_bounds__(256) void proj_kernel(const float* __restrict__ batch,
                                                   const float* __restrict__ proj,
                                                   float* __restrict__ t) {
    const int lane = threadIdx.x & 63;
    const int wave = __builtin_amdgcn_readfirstlane(threadIdx.x >> 6);
    const int row0 = blockIdx.x * 64 + wave * 16;
    const int kbase = blockIdx.y * KSLICE;

    float acc[16];
#pragma unroll
    for (int i = 0; i < 16; ++i) acc[i] = 0.0f;

    for (int k = kbase; k < kbase + KSLICE; k += 4) {
        const float pv0 = proj[(size_t)(k + 0) * RR + lane];
        const float pv1 = proj[(size_t)(k + 1) * RR + lane];
        const float pv2 = proj[(size_t)(k + 2) * RR + lane];
        const float pv3 = proj[(size_t)(k + 3) * RR + lane];
#pragma unroll
        for (int rr = 0; rr < 16; ++rr) {
            const float4 a =
                *reinterpret_cast<const float4*>(&batch[(size_t)(row0 + rr) * DD + k]);
            float s = acc[rr];
            s = fmaf(a.x, pv0, s);
            s = fmaf(a.y, pv1, s);
            s = fmaf(a.z, pv2, s);
            s = fmaf(a.w, pv3, s);
            acc[rr] = s;
        }
    }
#pragma unroll
    for (int rr = 0; rr < 16; ++rr) {
        atomicAdd(&t[(size_t)(row0 + rr) * RR + lane], acc[rr]);
    }
}

// ---------------------------------------------------------------------------
// Kernel B: out[b][i][j] = n_i + n_j - 2 * t_i . t_j
// grid (S/64, S/64, B), block 256. 64x64 output tile per block.
// t tiles staged TRANSPOSED in LDS: tiT[r][row], pad 68 (272B rows,
// 16B-aligned) -> conflict-free ds_read_b128 in the main loop.
// ---------------------------------------------------------------------------
#define TPAD 68

__global__ __launch_bounds__(256) void dist_kernel(const float* __restrict__ t,
                                                   float* __restrict__ out) {
    __shared__ __align__(16) float tiT[RR][TPAD];
    __shared__ __align__(16) float tjT[RR][TPAD];
    __shared__ float ni[64];
    __shared__ float nj[64];

    const int b  = blockIdx.z;
    const int i0 = blockIdx.y * 64;
    const int j0 = blockIdx.x * 64;
    const int tid = threadIdx.x;

    // Stage both tiles transposed: 2 tiles x 64 rows x 16 float4 = 2048 vec4
    for (int idx = tid; idx < 2048; idx += 256) {
        const int tile = idx >> 10;          // 0 = i-tile, 1 = j-tile
        const int e    = idx & 1023;
        const int row  = e >> 4;             // 0..63
        const int rseg = e & 15;             // 0..15 (float4 along r)
        const int src_row = b * SS + (tile ? j0 : i0) + row;
        const float4 v =
            *reinterpret_cast<const float4*>(&t[(size_t)src_row * RR + rseg * 4]);
        float (*dst)[TPAD] = tile ? tjT : tiT;
        dst[rseg * 4 + 0][row] = v.x;
        dst[rseg * 4 + 1][row] = v.y;
        dst[rseg * 4 + 2][row] = v.z;
        dst[rseg * 4 + 3][row] = v.w;
    }
    __syncthreads();

    // Norms from the staged tiles (threads 0..127)
    if (tid < 128) {
        const int row = tid & 63;
        float (*src)[TPAD] = (tid >> 6) ? tjT : tiT;
        float s = 0.0f;
#pragma unroll
        for (int r = 0; r < RR; ++r) {
            const float v = src[r][row];
            s = fmaf(v, v, s);
        }
        if (tid >> 6) nj[row] = s; else ni[row] = s;
    }
    __syncthreads();

    // 4x4 register tile per thread: 16x16 thread grid over the 64x64 tile
    const int tx = tid & 15;
    const int ty = tid >> 4;

    float acc[4][4];
#pragma unroll
    for (int i = 0; i < 4; ++i)
#pragma unroll
        for (int j = 0; j < 4; ++j) acc[i][j] = 0.0f;

#pragma unroll 4
    for (int r = 0; r < RR; ++r) {
        const float4 av = *reinterpret_cast<const float4*>(&tiT[r][ty * 4]);
        const float4 bv = *reinterpret_cast<const float4*>(&tjT[r][tx * 4]);
        const float a[4] = {av.x, av.y, av.z, av.w};
        const float c[4] = {bv.x, bv.y, bv.z, bv.w};
#pragma unroll
        for (int i = 0; i < 4; ++i)
#pragma unroll
            for (int j = 0; j < 4; ++j)
                acc[i][j] = fmaf(a[i], c[j], acc[i][j]);
    }

    // Epilogue: d = n_i + n_j - 2*G
    const float nrow[4] = {ni[ty * 4 + 0], ni[ty * 4 + 1], ni[ty * 4 + 2], ni[ty * 4 + 3]};
    const float ncol[4] = {nj[tx * 4 + 0], nj[tx * 4 + 1], nj[tx * 4 + 2], nj[tx * 4 + 3]};
#pragma unroll
    for (int i = 0; i < 4; ++i) {
        float4 o;
        o.x = fmaf(-2.0f, acc[i][0], nrow[i] + ncol[0]);
        o.y = fmaf(-2.0f, acc[i][1], nrow[i] + ncol[1]);
        o.z = fmaf(-2.0f, acc[i][2], nrow[i] + ncol[2]);
        o.w = fmaf(-2.0f, acc[i][3], nrow[i] + ncol[3]);
        *reinterpret_cast<float4*>(
            &out[((size_t)(b * SS + i0 + ty * 4 + i)) * SS + j0 + tx * 4]) = o;
    }
}

// ---------------------------------------------------------------------------
extern "C" void kernel_launch(void* const* d_in, const int* in_sizes, int n_in,
                              void* d_out, int out_size, void* d_ws, size_t ws_size,
                              hipStream_t stream) {
    const float* batch = (const float*)d_in[0];  // (4,1024,1024) f32
    const float* proj  = (const float*)d_in[1];  // (1024,64) f32
    float* out = (float*)d_out;                  // (4,1024,1024) f32
    float* t   = (float*)d_ws;                   // (4096,64) f32 scratch

    hipMemsetAsync(t, 0, (size_t)NROWS * RR * sizeof(float), stream);

    dim3 gA(NROWS / 64, KSPLIT, 1);
    proj_kernel<<<gA, 256, 0, stream>>>(batch, proj, t);

    dim3 gB(SS / 64, SS / 64, NB);
    dist_kernel<<<gB, 256, 0, stream>>>(t, out);
}

// Round 2
// 62.124 us; speedup vs baseline: 1.0128x; 1.0128x over previous
//
#include <hip/hip_runtime.h>

// Problem constants (B,S,D,R) = (4,1024,1024,64)
#define SS 1024
#define DD 1024
#define RR 64
#define NB 4
#define NROWS (NB * SS)   // 4096

// ---------------------------------------------------------------------------
// Kernel A v2: t[row][r] = sum_k batch[row][k] * proj[k][r]
// LDS-tiled GEMM on the VECTOR path (v1 streamed batch through the scalar
// cache -> 54us at 6% VALU). 64 rows x 64 cols per block, KSPLIT=8 K-split
// with fp32 atomicAdd combine. Batch tile staged TRANSPOSED AT[k][row]
// (stride 68 -> 16B-aligned rows; compute read = b128 broadcast). proj tile
// is a contiguous 16KB chunk -> linear conflict-free copy. Reg-staged
// prefetch of tile 1 hides global latency under tile-0 compute.
// ---------------------------------------------------------------------------
#define PROJ_ROWS 64
#define PROJ_BK 64
#define PROJ_KSPLIT 8
#define PROJ_KSLICE (DD / PROJ_KSPLIT)  // 128 = 2 tiles of BK=64
#define ATSTRIDE 68

__global__ __launch_bounds__(256) void proj_kernel(const float* __restrict__ batch,
                                                   const float* __restrict__ proj,
                                                   float* __restrict__ t) {
    __shared__ __align__(16) float AT[PROJ_BK][ATSTRIDE];  // 17.4 KB
    __shared__ __align__(16) float Pt[PROJ_BK][RR];        // 16 KB

    const int tid  = threadIdx.x;
    const int row0 = blockIdx.x * PROJ_ROWS;
    const int kbase = blockIdx.y * PROJ_KSLICE;

    const int tx = tid & 15;   // col group: cols tx*4..+3
    const int ty = tid >> 4;   // row group: rows ty*4..+3
    const int srow = ty;       // staging: row within 16-row group
    const int sk4  = tx;       // staging: float4 index along k

    float acc[4][4] = {{0.0f}};

    float4 a_reg[4], p_reg[4];

    auto load_tile = [&](int kt) {
        const int kt0 = kbase + kt * PROJ_BK;
#pragma unroll
        for (int i = 0; i < 4; ++i) {
            a_reg[i] = *reinterpret_cast<const float4*>(
                &batch[(size_t)(row0 + i * 16 + srow) * DD + kt0 + sk4 * 4]);
            p_reg[i] = reinterpret_cast<const float4*>(
                &proj[(size_t)kt0 * RR])[i * 256 + tid];
        }
    };
    auto write_tile = [&]() {
#pragma unroll
        for (int i = 0; i < 4; ++i) {
            AT[sk4 * 4 + 0][i * 16 + srow] = a_reg[i].x;
            AT[sk4 * 4 + 1][i * 16 + srow] = a_reg[i].y;
            AT[sk4 * 4 + 2][i * 16 + srow] = a_reg[i].z;
            AT[sk4 * 4 + 3][i * 16 + srow] = a_reg[i].w;
            reinterpret_cast<float4*>(Pt)[i * 256 + tid] = p_reg[i];
        }
    };
    auto compute = [&]() {
#pragma unroll 8
        for (int k = 0; k < PROJ_BK; ++k) {
            const float4 av = *reinterpret_cast<const float4*>(&AT[k][ty * 4]);
            const float4 pv = *reinterpret_cast<const float4*>(&Pt[k][tx * 4]);
            const float a[4] = {av.x, av.y, av.z, av.w};
            const float p[4] = {pv.x, pv.y, pv.z, pv.w};
#pragma unroll
            for (int i = 0; i < 4; ++i)
#pragma unroll
                for (int j = 0; j < 4; ++j)
                    acc[i][j] = fmaf(a[i], p[j], acc[i][j]);
        }
    };

    load_tile(0);
    write_tile();
    __syncthreads();
    load_tile(1);        // prefetch tile 1 into regs (hidden under compute)
    compute();           // tile 0
    __syncthreads();
    write_tile();
    __syncthreads();
    compute();           // tile 1

#pragma unroll
    for (int i = 0; i < 4; ++i)
#pragma unroll
        for (int j = 0; j < 4; ++j)
            atomicAdd(&t[(size_t)(row0 + ty * 4 + i) * RR + tx * 4 + j], acc[i][j]);
}

// ---------------------------------------------------------------------------
// Kernel B (unchanged, passing): out[b][i][j] = n_i + n_j - 2 * t_i . t_j
// ---------------------------------------------------------------------------
#define TPAD 68

__global__ __launch_bounds__(256) void dist_kernel(const float* __restrict__ t,
                                                   float* __restrict__ out) {
    __shared__ __align__(16) float tiT[RR][TPAD];
    __shared__ __align__(16) float tjT[RR][TPAD];
    __shared__ float ni[64];
    __shared__ float nj[64];

    const int b  = blockIdx.z;
    const int i0 = blockIdx.y * 64;
    const int j0 = blockIdx.x * 64;
    const int tid = threadIdx.x;

    for (int idx = tid; idx < 2048; idx += 256) {
        const int tile = idx >> 10;
        const int e    = idx & 1023;
        const int row  = e >> 4;
        const int rseg = e & 15;
        const int src_row = b * SS + (tile ? j0 : i0) + row;
        const float4 v =
            *reinterpret_cast<const float4*>(&t[(size_t)src_row * RR + rseg * 4]);
        float (*dst)[TPAD] = tile ? tjT : tiT;
        dst[rseg * 4 + 0][row] = v.x;
        dst[rseg * 4 + 1][row] = v.y;
        dst[rseg * 4 + 2][row] = v.z;
        dst[rseg * 4 + 3][row] = v.w;
    }
    __syncthreads();

    if (tid < 128) {
        const int row = tid & 63;
        float (*src)[TPAD] = (tid >> 6) ? tjT : tiT;
        float s = 0.0f;
#pragma unroll
        for (int r = 0; r < RR; ++r) {
            const float v = src[r][row];
            s = fmaf(v, v, s);
        }
        if (tid >> 6) nj[row] = s; else ni[row] = s;
    }
    __syncthreads();

    const int tx = tid & 15;
    const int ty = tid >> 4;

    float acc[4][4];
#pragma unroll
    for (int i = 0; i < 4; ++i)
#pragma unroll
        for (int j = 0; j < 4; ++j) acc[i][j] = 0.0f;

#pragma unroll 4
    for (int r = 0; r < RR; ++r) {
        const float4 av = *reinterpret_cast<const float4*>(&tiT[r][ty * 4]);
        const float4 bv = *reinterpret_cast<const float4*>(&tjT[r][tx * 4]);
        const float a[4] = {av.x, av.y, av.z, av.w};
        const float c[4] = {bv.x, bv.y, bv.z, bv.w};
#pragma unroll
        for (int i = 0; i < 4; ++i)
#pragma unroll
            for (int j = 0; j < 4; ++j)
                acc[i][j] = fmaf(a[i], c[j], acc[i][j]);
    }

    const float nrow[4] = {ni[ty * 4 + 0], ni[ty * 4 + 1], ni[ty * 4 + 2], ni[ty * 4 + 3]};
    const float ncol[4] = {nj[tx * 4 + 0], nj[tx * 4 + 1], nj[tx * 4 + 2], nj[tx * 4 + 3]};
#pragma unroll
    for (int i = 0; i < 4; ++i) {
        float4 o;
        o.x = fmaf(-2.0f, acc[i][0], nrow[i] + ncol[0]);
        o.y = fmaf(-2.0f, acc[i][1], nrow[i] + ncol[1]);
        o.z = fmaf(-2.0f, acc[i][2], nrow[i] + ncol[2]);
        o.w = fmaf(-2.0f, acc[i][3], nrow[i] + ncol[3]);
        *reinterpret_cast<float4*>(
            &out[((size_t)(b * SS + i0 + ty * 4 + i)) * SS + j0 + tx * 4]) = o;
    }
}

// ---------------------------------------------------------------------------
extern "C" void kernel_launch(void* const* d_in, const int* in_sizes, int n_in,
                              void* d_out, int out_size, void* d_ws, size_t ws_size,
                              hipStream_t stream) {
    const float* batch = (const float*)d_in[0];  // (4,1024,1024) f32
    const float* proj  = (const float*)d_in[1];  // (1024,64) f32
    float* out = (float*)d_out;                  // (4,1024,1024) f32
    float* t   = (float*)d_ws;                   // (4096,64) f32 scratch

    hipMemsetAsync(t, 0, (size_t)NROWS * RR * sizeof(float), stream);

    dim3 gA(NROWS / PROJ_ROWS, PROJ_KSPLIT, 1);
    proj_kernel<<<gA, 256, 0, stream>>>(batch, proj, t);

    dim3 gB(SS / 64, SS / 64, NB);
    dist_kernel<<<gB, 256, 0, stream>>>(t, out);
}

// Round 6
// 41.397 us; speedup vs baseline: 1.5199x; 1.5007x over previous
//
#include <hip/hip_runtime.h>

// Problem constants (B,S,D,R) = (4,1024,1024,64)
#define SS 1024
#define DD 1024
#define RR 64
#define NB 4
#define NROWS (NB * SS)   // 4096

#define PROJ_ROWS 64
#define PROJ_BK 64
#define PROJ_KSPLIT 8
#define PROJ_KSLICE (DD / PROJ_KSPLIT)  // 128 = 2 tiles of BK=64
#define ATSTRIDE 68

#define PART_ELEMS ((size_t)PROJ_KSPLIT * NROWS * RR)          // 2M floats = 8 MB
#define WS_NEED ((PART_ELEMS + (size_t)NROWS * RR) * 4)        // 9 MB

// ---------------------------------------------------------------------------
// Kernel A: t[row][r] = sum_k batch[row][k] * proj[k][r]
// LDS-tiled vector-path GEMM, 64 rows x 64 cols per block, K split 8-way.
// ATOMIC=false: write per-slice partials (plain stores, no init needed).
// ATOMIC=true : fallback (small ws) — atomicAdd into pre-zeroed t.
// ---------------------------------------------------------------------------
template <bool ATOMIC>
__global__ __launch_bounds__(256) void proj_kernel(const float* __restrict__ batch,
                                                   const float* __restrict__ proj,
                                                   float* __restrict__ dst) {
    __shared__ __align__(16) float AT[PROJ_BK][ATSTRIDE];  // 17.4 KB
    __shared__ __align__(16) float Pt[PROJ_BK][RR];        // 16 KB

    const int tid  = threadIdx.x;
    const int row0 = blockIdx.x * PROJ_ROWS;
    const int kbase = blockIdx.y * PROJ_KSLICE;

    const int tx = tid & 15;   // col group: cols tx*4..+3
    const int ty = tid >> 4;   // row group: rows ty*4..+3
    const int srow = ty;       // staging: row within 16-row group
    const int sk4  = tx;       // staging: float4 index along k

    float acc[4][4] = {{0.0f}};
    float4 a_reg[4], p_reg[4];

    auto load_tile = [&](int kt) {
        const int kt0 = kbase + kt * PROJ_BK;
#pragma unroll
        for (int i = 0; i < 4; ++i) {
            a_reg[i] = *reinterpret_cast<const float4*>(
                &batch[(size_t)(row0 + i * 16 + srow) * DD + kt0 + sk4 * 4]);
            p_reg[i] = reinterpret_cast<const float4*>(
                &proj[(size_t)kt0 * RR])[i * 256 + tid];
        }
    };
    auto write_tile = [&]() {
#pragma unroll
        for (int i = 0; i < 4; ++i) {
            AT[sk4 * 4 + 0][i * 16 + srow] = a_reg[i].x;
            AT[sk4 * 4 + 1][i * 16 + srow] = a_reg[i].y;
            AT[sk4 * 4 + 2][i * 16 + srow] = a_reg[i].z;
            AT[sk4 * 4 + 3][i * 16 + srow] = a_reg[i].w;
            reinterpret_cast<float4*>(Pt)[i * 256 + tid] = p_reg[i];
        }
    };
    auto compute = [&]() {
#pragma unroll 8
        for (int k = 0; k < PROJ_BK; ++k) {
            const float4 av = *reinterpret_cast<const float4*>(&AT[k][ty * 4]);
            const float4 pv = *reinterpret_cast<const float4*>(&Pt[k][tx * 4]);
            const float a[4] = {av.x, av.y, av.z, av.w};
            const float p[4] = {pv.x, pv.y, pv.z, pv.w};
#pragma unroll
            for (int i = 0; i < 4; ++i)
#pragma unroll
                for (int j = 0; j < 4; ++j)
                    acc[i][j] = fmaf(a[i], p[j], acc[i][j]);
        }
    };

    load_tile(0);
    write_tile();
    __syncthreads();
    load_tile(1);        // prefetch tile 1 into regs (hidden under compute)
    compute();           // tile 0
    __syncthreads();
    write_tile();
    __syncthreads();
    compute();           // tile 1

    if (ATOMIC) {
#pragma unroll
        for (int i = 0; i < 4; ++i)
#pragma unroll
            for (int j = 0; j < 4; ++j)
                atomicAdd(&dst[(size_t)(row0 + ty * 4 + i) * RR + tx * 4 + j],
                          acc[i][j]);
    } else {
        float* slice = dst + (size_t)blockIdx.y * NROWS * RR;
#pragma unroll
        for (int i = 0; i < 4; ++i) {
            float4 o = {acc[i][0], acc[i][1], acc[i][2], acc[i][3]};
            *reinterpret_cast<float4*>(
                &slice[(size_t)(row0 + ty * 4 + i) * RR + tx * 4]) = o;
        }
    }
}

// Sum the 8 K-slice partials -> t. 64K float4 outputs, one per thread.
__global__ __launch_bounds__(256) void reduce_kernel(const float* __restrict__ part,
                                                     float* __restrict__ t) {
    const int idx = blockIdx.x * 256 + threadIdx.x;  // float4 index, 0..65535
    const float4* p4 = reinterpret_cast<const float4*>(part);
    float4 s = p4[idx];
#pragma unroll
    for (int kb = 1; kb < PROJ_KSPLIT; ++kb) {
        const float4 v = p4[(size_t)kb * (NROWS * RR / 4) + idx];
        s.x += v.x; s.y += v.y; s.z += v.z; s.w += v.w;
    }
    reinterpret_cast<float4*>(t)[idx] = s;
}

// Fallback zero-fill (own kernel: runtime's fillBuffer took 44us for 1 MB)
__global__ __launch_bounds__(256) void zero_kernel(float* __restrict__ t) {
    const int idx = blockIdx.x * 256 + threadIdx.x;
    reinterpret_cast<float4*>(t)[idx] = {0.0f, 0.0f, 0.0f, 0.0f};
}

// ---------------------------------------------------------------------------
// Kernel B (unchanged): out[b][i][j] = n_i + n_j - 2 * t_i . t_j
// ---------------------------------------------------------------------------
#define TPAD 68

__global__ __launch_bounds__(256) void dist_kernel(const float* __restrict__ t,
                                                   float* __restrict__ out) {
    __shared__ __align__(16) float tiT[RR][TPAD];
    __shared__ __align__(16) float tjT[RR][TPAD];
    __shared__ float ni[64];
    __shared__ float nj[64];

    const int b  = blockIdx.z;
    const int i0 = blockIdx.y * 64;
    const int j0 = blockIdx.x * 64;
    const int tid = threadIdx.x;

    for (int idx = tid; idx < 2048; idx += 256) {
        const int tile = idx >> 10;
        const int e    = idx & 1023;
        const int row  = e >> 4;
        const int rseg = e & 15;
        const int src_row = b * SS + (tile ? j0 : i0) + row;
        const float4 v =
            *reinterpret_cast<const float4*>(&t[(size_t)src_row * RR + rseg * 4]);
        float (*dst)[TPAD] = tile ? tjT : tiT;
        dst[rseg * 4 + 0][row] = v.x;
        dst[rseg * 4 + 1][row] = v.y;
        dst[rseg * 4 + 2][row] = v.z;
        dst[rseg * 4 + 3][row] = v.w;
    }
    __syncthreads();

    if (tid < 128) {
        const int row = tid & 63;
        float (*src)[TPAD] = (tid >> 6) ? tjT : tiT;
        float s = 0.0f;
#pragma unroll
        for (int r = 0; r < RR; ++r) {
            const float v = src[r][row];
            s = fmaf(v, v, s);
        }
        if (tid >> 6) nj[row] = s; else ni[row] = s;
    }
    __syncthreads();

    const int tx = tid & 15;
    const int ty = tid >> 4;

    float acc[4][4];
#pragma unroll
    for (int i = 0; i < 4; ++i)
#pragma unroll
        for (int j = 0; j < 4; ++j) acc[i][j] = 0.0f;

#pragma unroll 4
    for (int r = 0; r < RR; ++r) {
        const float4 av = *reinterpret_cast<const float4*>(&tiT[r][ty * 4]);
        const float4 bv = *reinterpret_cast<const float4*>(&tjT[r][tx * 4]);
        const float a[4] = {av.x, av.y, av.z, av.w};
        const float c[4] = {bv.x, bv.y, bv.z, bv.w};
#pragma unroll
        for (int i = 0; i < 4; ++i)
#pragma unroll
            for (int j = 0; j < 4; ++j)
                acc[i][j] = fmaf(a[i], c[j], acc[i][j]);
    }

    const float nrow[4] = {ni[ty * 4 + 0], ni[ty * 4 + 1], ni[ty * 4 + 2], ni[ty * 4 + 3]};
    const float ncol[4] = {nj[tx * 4 + 0], nj[tx * 4 + 1], nj[tx * 4 + 2], nj[tx * 4 + 3]};
#pragma unroll
    for (int i = 0; i < 4; ++i) {
        float4 o;
        o.x = fmaf(-2.0f, acc[i][0], nrow[i] + ncol[0]);
        o.y = fmaf(-2.0f, acc[i][1], nrow[i] + ncol[1]);
        o.z = fmaf(-2.0f, acc[i][2], nrow[i] + ncol[2]);
        o.w = fmaf(-2.0f, acc[i][3], nrow[i] + ncol[3]);
        *reinterpret_cast<float4*>(
            &out[((size_t)(b * SS + i0 + ty * 4 + i)) * SS + j0 + tx * 4]) = o;
    }
}

// ---------------------------------------------------------------------------
extern "C" void kernel_launch(void* const* d_in, const int* in_sizes, int n_in,
                              void* d_out, int out_size, void* d_ws, size_t ws_size,
                              hipStream_t stream) {
    const float* batch = (const float*)d_in[0];  // (4,1024,1024) f32
    const float* proj  = (const float*)d_in[1];  // (1024,64) f32
    float* out = (float*)d_out;                  // (4,1024,1024) f32

    dim3 gA(NROWS / PROJ_ROWS, PROJ_KSPLIT, 1);
    dim3 gB(SS / 64, SS / 64, NB);

    if (ws_size >= WS_NEED) {
        // Main path: partials + reduce, no memset, no atomics.
        float* part = (float*)d_ws;               // 8 MB
        float* t    = part + PART_ELEMS;          // 1 MB
        proj_kernel<false><<<gA, 256, 0, stream>>>(batch, proj, part);
        reduce_kernel<<<NROWS * RR / (256 * 4), 256, 0, stream>>>(part, t);
        dist_kernel<<<gB, 256, 0, stream>>>(t, out);
    } else {
        // Fallback: own zero kernel + atomic combine.
        float* t = (float*)d_ws;                  // 1 MB
        zero_kernel<<<NROWS * RR / (256 * 4), 256, 0, stream>>>(t);
        proj_kernel<true><<<gA, 256, 0, stream>>>(batch, proj, t);
        dist_kernel<<<gB, 256, 0, stream>>>(t, out);
    }
}